// Round 2
// baseline (1430.238 us; speedup 1.0000x reference)
//
#include <hip/hip_runtime.h>
#include <hip/hip_cooperative_groups.h>

namespace cg = cooperative_groups;

// CFConv, round 6. Whole-pipeline mega-fusion:
//  - ONE cooperative kernel (1024 blocks = 4/CU resident) replaces 9 dispatches
//    phases: zero(count) | node_linear(blk<625) + hist(blk>=625) + zero(out)
//            | scan1 | scan2 | scan3 | scatter | edge-fused loop
//    separated by cg::grid.sync() (+ __threadfence for cross-XCD visibility)
//  - edge phase identical to round 5 (dst-sorted order, in-register segmented
//    scan, fp32 atomic flushes)
//  - fallback: round-5 multi-kernel pipeline if cooperative launch fails

#define N_NODES 40000
#define N_EDGES 640000
#define IN_CH 128
#define OUT_CH 128
#define NUM_RBF 64

#define TILE_M 64
#define NTILES (N_EDGES / TILE_M)     // 10000 exact
#define NB_NODE (N_NODES / TILE_M)    // 625 node-linear tiles
#define RBF_STR 72   // ushorts
#define T_STR 136    // ushorts
#define HV_STR 136   // ushorts
#define W1_STR 72
#define W2_STR 136
#define NSCB ((N_NODES + 255) / 256)  // 157 scan blocks
#define EDGE_GRID 1024                // 4 blocks/CU x 256 CUs, persistent

typedef __attribute__((ext_vector_type(8))) short bf16x8;
typedef __attribute__((ext_vector_type(16))) float f32x16;

__device__ __forceinline__ unsigned short f2bf(float f) {
  unsigned u = __float_as_uint(f);
  return (unsigned short)((u + 0x7FFFu + ((u >> 16) & 1u)) >> 16);
}
__device__ __forceinline__ float bf2f(unsigned short s) {
  return __uint_as_float(((unsigned)s) << 16);
}

// ---------------------------------------------------------------------------
// MEGA KERNEL (cooperative): full pipeline in one dispatch
// ---------------------------------------------------------------------------
__global__ __launch_bounds__(256, 4) void mega_kernel(
    const float* __restrict__ x, const int* __restrict__ eidx,
    const float* __restrict__ rbf, const float* __restrict__ W1,
    const float* __restrict__ b1, const float* __restrict__ W2,
    const float* __restrict__ b2, const float* __restrict__ Wl,
    const float* __restrict__ bl, unsigned short* __restrict__ hbf,
    int* __restrict__ eperm, int* __restrict__ dsts, int* __restrict__ cols,
    int* __restrict__ count, int* __restrict__ cursor, int* __restrict__ tscan,
    int* __restrict__ bsum, int* __restrict__ boff, float* __restrict__ outp) {
  cg::grid_group grid = cg::this_grid();
  __shared__ __align__(16) char pool[IN_CH * W2_STR * 2];  // 34816 B

  const int t = threadIdx.x;
  const int bid = blockIdx.x;
  const int gsz = gridDim.x;  // 1024
  const int gtid = bid * 256 + t;
  const int gthreads = gsz * 256;
  const int lane = t & 63;
  const int l31 = lane & 31;
  const int lhalf = lane >> 5;
  const int wv = t >> 6;
  const int nbase = wv * 32 + l31;

  const int* rowI = eidx;
  const int* colI = eidx + N_EDGES;

  // ---- Phase A: zero count -------------------------------------------------
  {
    int4 z = {0, 0, 0, 0};
    for (int i = gtid; i < N_NODES / 4; i += gthreads) ((int4*)count)[i] = z;
  }
  __threadfence();
  grid.sync();

  // ---- Phase B: node_linear (blk<625) | hist (blk>=625); all zero out ------
  if (bid < NB_NODE) {
    // h = bf16(x @ Wl + bl), one 64-row tile
    {
      unsigned short* sWT = (unsigned short*)pool;
      const int k2 = t >> 1;
      const int d0 = (t & 1) * 64;
#pragma unroll
      for (int i = 0; i < 16; ++i) {
        float4 v = *(const float4*)(Wl + k2 * OUT_CH + d0 + 4 * i);
        sWT[(d0 + 4 * i + 0) * W2_STR + k2] = f2bf(v.x);
        sWT[(d0 + 4 * i + 1) * W2_STR + k2] = f2bf(v.y);
        sWT[(d0 + 4 * i + 2) * W2_STR + k2] = f2bf(v.z);
        sWT[(d0 + 4 * i + 3) * W2_STR + k2] = f2bf(v.w);
      }
    }
    __syncthreads();
    bf16x8 BW[8];
    {
      const unsigned short* sWT = (const unsigned short*)pool;
#pragma unroll
      for (int kk = 0; kk < 8; ++kk)
        BW[kk] = *(const bf16x8*)&sWT[nbase * W2_STR + kk * 16 + lhalf * 8];
    }
    const float blv = bl[nbase];
    __syncthreads();

    const int rbase = bid * TILE_M;
    unsigned short* sX = (unsigned short*)pool;
    {
      const int m = t >> 2;
      const int c0 = (t & 3) * 32;
      const float* src = x + (size_t)(rbase + m) * IN_CH + c0;
#pragma unroll
      for (int i = 0; i < 8; ++i) {
        float4 v = *(const float4*)(src + 4 * i);
        ushort4 p;
        p.x = f2bf(v.x); p.y = f2bf(v.y); p.z = f2bf(v.z); p.w = f2bf(v.w);
        *(ushort4*)&sX[m * T_STR + c0 + 4 * i] = p;
      }
    }
    __syncthreads();
#pragma unroll
    for (int mt = 0; mt < 2; ++mt) {
      f32x16 acc = {0.f, 0.f, 0.f, 0.f, 0.f, 0.f, 0.f, 0.f,
                    0.f, 0.f, 0.f, 0.f, 0.f, 0.f, 0.f, 0.f};
#pragma unroll
      for (int kk = 0; kk < 8; ++kk) {
        bf16x8 A = *(const bf16x8*)&sX[(mt * 32 + l31) * T_STR + kk * 16 + lhalf * 8];
        acc = __builtin_amdgcn_mfma_f32_32x32x16_bf16(A, BW[kk], acc, 0, 0, 0);
      }
#pragma unroll
      for (int r = 0; r < 16; ++r) {
        const int rowm = mt * 32 + (r & 3) + 8 * (r >> 2) + 4 * lhalf;
        hbf[(size_t)(rbase + rowm) * OUT_CH + nbase] = f2bf(acc[r] + blv);
      }
    }
  } else {
    // histogram of dst
    for (int e = (bid - NB_NODE) * 256 + t; e < N_EDGES;
         e += (gsz - NB_NODE) * 256)
      atomicAdd(&count[rowI[e]], 1);
  }
  {
    float4 z = {0.f, 0.f, 0.f, 0.f};
    for (int i = gtid; i < N_NODES * OUT_CH / 4; i += gthreads)
      ((float4*)outp)[i] = z;
  }
  __threadfence();
  grid.sync();

  // ---- Phase C: scan1 (per-256-chunk inclusive scan) -----------------------
  if (bid < NSCB) {
    int* s = (int*)pool;
    const int i = bid * 256 + t;
    const int v = (i < N_NODES) ? count[i] : 0;
    s[t] = v;
    __syncthreads();
    for (int off = 1; off < 256; off <<= 1) {
      int u = (t >= off) ? s[t - off] : 0;
      __syncthreads();
      s[t] += u;
      __syncthreads();
    }
    if (i < N_NODES) tscan[i] = s[t];
    if (t == 255) bsum[bid] = s[255];
  }
  __threadfence();
  grid.sync();

  // ---- Phase D: scan2 (block offsets, exclusive) ---------------------------
  if (bid == 0) {
    int* s = (int*)pool;
    const int v = (t < NSCB) ? bsum[t] : 0;
    s[t] = v;
    __syncthreads();
    for (int off = 1; off < 256; off <<= 1) {
      int u = (t >= off) ? s[t - off] : 0;
      __syncthreads();
      s[t] += u;
      __syncthreads();
    }
    if (t < NSCB) boff[t] = s[t] - v;  // exclusive
  }
  __threadfence();
  grid.sync();

  // ---- Phase E: scan3 (cursor = exclusive start per node) ------------------
  if (bid < NSCB) {
    const int i = bid * 256 + t;
    if (i < N_NODES) cursor[i] = boff[bid] + tscan[i] - count[i];
  }
  __threadfence();
  grid.sync();

  // ---- Phase F: scatter (sorted permutation + dst/col arrays) --------------
  for (int e = gtid; e < N_EDGES; e += gthreads) {
    const int r = rowI[e];
    const int p = atomicAdd(&cursor[r], 1);
    eperm[p] = e;
    dsts[p] = r;
    cols[p] = colI[e];
  }
  __threadfence();
  grid.sync();

  // ---- Phase G: fused filter + modulate + segmented reduce -----------------
  unsigned short* sHv = (unsigned short*)pool;                            // 17408
  unsigned short* sT = (unsigned short*)pool;                             // overlap
  unsigned short* sRbf = (unsigned short*)(pool + TILE_M * HV_STR * 2);   // 9216
  int* sAux = (int*)(pool + TILE_M * HV_STR * 2 + TILE_M * RBF_STR * 2);  // 256

  // weight fragments (pool reused twice)
  {
    unsigned short* sW1T = (unsigned short*)pool;
    const int k = t >> 2;
    const int c0 = (t & 3) * 32;
#pragma unroll
    for (int i = 0; i < 8; ++i) {
      float4 v = *(const float4*)(W1 + k * OUT_CH + c0 + 4 * i);
      sW1T[(c0 + 4 * i + 0) * W1_STR + k] = f2bf(v.x);
      sW1T[(c0 + 4 * i + 1) * W1_STR + k] = f2bf(v.y);
      sW1T[(c0 + 4 * i + 2) * W1_STR + k] = f2bf(v.z);
      sW1T[(c0 + 4 * i + 3) * W1_STR + k] = f2bf(v.w);
    }
  }
  __syncthreads();
  bf16x8 B1[4];
  {
    const unsigned short* sW1T = (const unsigned short*)pool;
#pragma unroll
    for (int kk = 0; kk < 4; ++kk)
      B1[kk] = *(const bf16x8*)&sW1T[nbase * W1_STR + kk * 16 + lhalf * 8];
  }
  __syncthreads();
  {
    unsigned short* sW2T = (unsigned short*)pool;
    const int k2 = t >> 1;
    const int d0 = (t & 1) * 64;
#pragma unroll
    for (int i = 0; i < 16; ++i) {
      float4 v = *(const float4*)(W2 + k2 * OUT_CH + d0 + 4 * i);
      sW2T[(d0 + 4 * i + 0) * W2_STR + k2] = f2bf(v.x);
      sW2T[(d0 + 4 * i + 1) * W2_STR + k2] = f2bf(v.y);
      sW2T[(d0 + 4 * i + 2) * W2_STR + k2] = f2bf(v.z);
      sW2T[(d0 + 4 * i + 3) * W2_STR + k2] = f2bf(v.w);
    }
  }
  __syncthreads();
  bf16x8 B2[8];
  {
    const unsigned short* sW2T = (const unsigned short*)pool;
#pragma unroll
    for (int kk = 0; kk < 8; ++kk)
      B2[kk] = *(const bf16x8*)&sW2T[nbase * W2_STR + kk * 16 + lhalf * 8];
  }
  const float b1v = b1[nbase];
  const float b2v = b2[nbase];

  for (int tile = bid; tile < NTILES; tile += gsz) {
    const int ebase = tile * TILE_M;
    __syncthreads();  // (a) prev GEMM2/sAux reads complete before restage

    // stage rbf (bf16, gathered via eperm) + h rows -> sHv + dst
    {
      const int m = t >> 2;
      const int ep = eperm[ebase + m];
      const int kq = (t & 3) * 16;
      const float* src = rbf + (size_t)ep * NUM_RBF + kq;
#pragma unroll
      for (int i = 0; i < 4; ++i) {
        float4 v = *(const float4*)(src + 4 * i);
        ushort4 p;
        p.x = f2bf(v.x); p.y = f2bf(v.y); p.z = f2bf(v.z); p.w = f2bf(v.w);
        *(ushort4*)&sRbf[m * RBF_STR + kq + 4 * i] = p;
      }
#pragma unroll
      for (int i = 0; i < 4; ++i) {
        const int chunk = t + 256 * i;
        const int row = chunk >> 4;
        const int c8 = (chunk & 15) * 8;  // ushort offset within row
        const int col = cols[ebase + row];
        *(uint4*)&sHv[row * HV_STR + c8] =
            *(const uint4*)(hbf + (size_t)col * OUT_CH + c8);
      }
      if (t < TILE_M) sAux[t] = dsts[ebase + t];
    }
    __syncthreads();  // (b)

    // h values from LDS (read BEFORE sT overwrites sHv)
    float hv[2][16];
#pragma unroll
    for (int mt = 0; mt < 2; ++mt)
#pragma unroll
      for (int r = 0; r < 16; ++r) {
        const int rowm = mt * 32 + (r & 3) + 8 * (r >> 2) + 4 * lhalf;
        hv[mt][r] = bf2f(sHv[rowm * HV_STR + nbase]);
      }
    __syncthreads();  // (b2) sHv reads done; sT may overwrite

    // GEMM1: sT = bf16(relu(rbf @ W1 + b1))
#pragma unroll
    for (int mt = 0; mt < 2; ++mt) {
      f32x16 acc = {0.f, 0.f, 0.f, 0.f, 0.f, 0.f, 0.f, 0.f,
                    0.f, 0.f, 0.f, 0.f, 0.f, 0.f, 0.f, 0.f};
#pragma unroll
      for (int kk = 0; kk < 4; ++kk) {
        bf16x8 A = *(const bf16x8*)&sRbf[(mt * 32 + l31) * RBF_STR + kk * 16 + lhalf * 8];
        acc = __builtin_amdgcn_mfma_f32_32x32x16_bf16(A, B1[kk], acc, 0, 0, 0);
      }
#pragma unroll
      for (int r = 0; r < 16; ++r) {
        const int rowm = (r & 3) + 8 * (r >> 2) + 4 * lhalf;
        float v = acc[r] + b1v;
        v = v > 0.f ? v : 0.f;
        sT[(mt * 32 + rowm) * T_STR + nbase] = f2bf(v);
      }
    }
    __syncthreads();  // (c)

    // GEMM2 + modulate + in-register segmented reduce
    float sum = 0.f;
    int curd = -1;
#pragma unroll
    for (int mt = 0; mt < 2; ++mt) {
      f32x16 acc = {0.f, 0.f, 0.f, 0.f, 0.f, 0.f, 0.f, 0.f,
                    0.f, 0.f, 0.f, 0.f, 0.f, 0.f, 0.f, 0.f};
#pragma unroll
      for (int kk = 0; kk < 8; ++kk) {
        bf16x8 A = *(const bf16x8*)&sT[(mt * 32 + l31) * T_STR + kk * 16 + lhalf * 8];
        acc = __builtin_amdgcn_mfma_f32_32x32x16_bf16(A, B2[kk], acc, 0, 0, 0);
      }
#pragma unroll
      for (int r = 0; r < 16; ++r) {
        const int rowm = mt * 32 + (r & 3) + 8 * (r >> 2) + 4 * lhalf;
        const float m = hv[mt][r] * (acc[r] + b2v);
        const int d = sAux[rowm];
        if (d != curd) {
          if (curd >= 0) atomicAdd(&outp[(size_t)curd * OUT_CH + nbase], sum);
          curd = d;
          sum = m;
        } else {
          sum += m;
        }
      }
    }
    atomicAdd(&outp[(size_t)curd * OUT_CH + nbase], sum);
  }
}

// ---------------------------------------------------------------------------
// Fallback pipeline kernels (round-5, used if cooperative launch unavailable)
// ---------------------------------------------------------------------------
__global__ __launch_bounds__(256) void node_linear_mfma(
    const float* __restrict__ x, const float* __restrict__ Wl,
    const float* __restrict__ bl, unsigned short* __restrict__ hbf) {
  __shared__ __align__(16) char pool[IN_CH * W2_STR * 2];
  const int t = threadIdx.x;
  const int lane = t & 63;
  const int l31 = lane & 31;
  const int lhalf = lane >> 5;
  const int wv = t >> 6;

  {
    unsigned short* sWT = (unsigned short*)pool;
    const int k2 = t >> 1;
    const int d0 = (t & 1) * 64;
#pragma unroll
    for (int i = 0; i < 16; ++i) {
      float4 v = *(const float4*)(Wl + k2 * OUT_CH + d0 + 4 * i);
      sWT[(d0 + 4 * i + 0) * W2_STR + k2] = f2bf(v.x);
      sWT[(d0 + 4 * i + 1) * W2_STR + k2] = f2bf(v.y);
      sWT[(d0 + 4 * i + 2) * W2_STR + k2] = f2bf(v.z);
      sWT[(d0 + 4 * i + 3) * W2_STR + k2] = f2bf(v.w);
    }
  }
  __syncthreads();
  const int nbase = wv * 32 + l31;
  bf16x8 BW[8];
  {
    const unsigned short* sWT = (const unsigned short*)pool;
#pragma unroll
    for (int kk = 0; kk < 8; ++kk)
      BW[kk] = *(const bf16x8*)&sWT[nbase * W2_STR + kk * 16 + lhalf * 8];
  }
  const float blv = bl[nbase];
  __syncthreads();

  const int rbase = blockIdx.x * TILE_M;
  unsigned short* sX = (unsigned short*)pool;
  {
    const int m = t >> 2;
    const int c0 = (t & 3) * 32;
    const float* src = x + (size_t)(rbase + m) * IN_CH + c0;
#pragma unroll
    for (int i = 0; i < 8; ++i) {
      float4 v = *(const float4*)(src + 4 * i);
      ushort4 p;
      p.x = f2bf(v.x); p.y = f2bf(v.y); p.z = f2bf(v.z); p.w = f2bf(v.w);
      *(ushort4*)&sX[m * T_STR + c0 + 4 * i] = p;
    }
  }
  __syncthreads();
#pragma unroll
  for (int mt = 0; mt < 2; ++mt) {
    f32x16 acc = {0.f, 0.f, 0.f, 0.f, 0.f, 0.f, 0.f, 0.f,
                  0.f, 0.f, 0.f, 0.f, 0.f, 0.f, 0.f, 0.f};
#pragma unroll
    for (int kk = 0; kk < 8; ++kk) {
      bf16x8 A = *(const bf16x8*)&sX[(mt * 32 + l31) * T_STR + kk * 16 + lhalf * 8];
      acc = __builtin_amdgcn_mfma_f32_32x32x16_bf16(A, BW[kk], acc, 0, 0, 0);
    }
#pragma unroll
    for (int r = 0; r < 16; ++r) {
      const int rowm = mt * 32 + (r & 3) + 8 * (r >> 2) + 4 * lhalf;
      hbf[(size_t)(rbase + rowm) * OUT_CH + nbase] = f2bf(acc[r] + blv);
    }
  }
}

__global__ void hist_kernel(const int* __restrict__ rowI, int* __restrict__ count) {
  int e = blockIdx.x * 256 + threadIdx.x;
  if (e < N_EDGES) atomicAdd(&count[rowI[e]], 1);
}

__global__ __launch_bounds__(256) void scan1_kernel(const int* __restrict__ count,
                                                    int* __restrict__ tscan,
                                                    int* __restrict__ bsum) {
  __shared__ int s[256];
  const int t = threadIdx.x;
  const int i = blockIdx.x * 256 + t;
  const int v = (i < N_NODES) ? count[i] : 0;
  s[t] = v;
  __syncthreads();
  for (int off = 1; off < 256; off <<= 1) {
    int u = (t >= off) ? s[t - off] : 0;
    __syncthreads();
    s[t] += u;
    __syncthreads();
  }
  if (i < N_NODES) tscan[i] = s[t];
  if (t == 255) bsum[blockIdx.x] = s[255];
}

__global__ __launch_bounds__(256) void scan2_kernel(const int* __restrict__ bsum,
                                                    int* __restrict__ boff) {
  __shared__ int s[256];
  const int t = threadIdx.x;
  const int v = (t < NSCB) ? bsum[t] : 0;
  s[t] = v;
  __syncthreads();
  for (int off = 1; off < 256; off <<= 1) {
    int u = (t >= off) ? s[t - off] : 0;
    __syncthreads();
    s[t] += u;
    __syncthreads();
  }
  if (t < NSCB) boff[t] = s[t] - v;  // exclusive
}

__global__ __launch_bounds__(256) void scan3_kernel(
    const int* __restrict__ count, const int* __restrict__ tscan,
    const int* __restrict__ boff, int* __restrict__ cursor) {
  const int i = blockIdx.x * 256 + threadIdx.x;
  if (i < N_NODES) cursor[i] = boff[blockIdx.x] + tscan[i] - count[i];
}

__global__ void scatter_kernel(const int* __restrict__ rowI,
                               const int* __restrict__ colI,
                               int* __restrict__ cursor,
                               int* __restrict__ eperm, int* __restrict__ dsts,
                               int* __restrict__ cols) {
  int e = blockIdx.x * 256 + threadIdx.x;
  if (e < N_EDGES) {
    const int r = rowI[e];
    const int p = atomicAdd(&cursor[r], 1);
    eperm[p] = e;
    dsts[p] = r;
    cols[p] = colI[e];
  }
}

template <bool SORTED>
__global__ __launch_bounds__(256, 4) void edge_fused_kernel(
    const int* __restrict__ eperm, const float* __restrict__ rbf,
    const float* __restrict__ W1, const float* __restrict__ b1,
    const float* __restrict__ W2, const float* __restrict__ b2,
    const unsigned short* __restrict__ hbf, const int* __restrict__ dsts,
    const int* __restrict__ cols, float* __restrict__ outp) {
  __shared__ __align__(16) char pool[IN_CH * W2_STR * 2];

  unsigned short* sHv = (unsigned short*)pool;
  unsigned short* sT = (unsigned short*)pool;
  unsigned short* sRbf = (unsigned short*)(pool + TILE_M * HV_STR * 2);
  int* sAux = (int*)(pool + TILE_M * HV_STR * 2 + TILE_M * RBF_STR * 2);

  const int t = threadIdx.x;
  const int lane = t & 63;
  const int l31 = lane & 31;
  const int lhalf = lane >> 5;
  const int wv = t >> 6;
  const int nbase = wv * 32 + l31;

  {
    unsigned short* sW1T = (unsigned short*)pool;
    const int k = t >> 2;
    const int c0 = (t & 3) * 32;
#pragma unroll
    for (int i = 0; i < 8; ++i) {
      float4 v = *(const float4*)(W1 + k * OUT_CH + c0 + 4 * i);
      sW1T[(c0 + 4 * i + 0) * W1_STR + k] = f2bf(v.x);
      sW1T[(c0 + 4 * i + 1) * W1_STR + k] = f2bf(v.y);
      sW1T[(c0 + 4 * i + 2) * W1_STR + k] = f2bf(v.z);
      sW1T[(c0 + 4 * i + 3) * W1_STR + k] = f2bf(v.w);
    }
  }
  __syncthreads();
  bf16x8 B1[4];
  {
    const unsigned short* sW1T = (const unsigned short*)pool;
#pragma unroll
    for (int kk = 0; kk < 4; ++kk)
      B1[kk] = *(const bf16x8*)&sW1T[nbase * W1_STR + kk * 16 + lhalf * 8];
  }
  __syncthreads();
  {
    unsigned short* sW2T = (unsigned short*)pool;
    const int k2 = t >> 1;
    const int d0 = (t & 1) * 64;
#pragma unroll
    for (int i = 0; i < 16; ++i) {
      float4 v = *(const float4*)(W2 + k2 * OUT_CH + d0 + 4 * i);
      sW2T[(d0 + 4 * i + 0) * W2_STR + k2] = f2bf(v.x);
      sW2T[(d0 + 4 * i + 1) * W2_STR + k2] = f2bf(v.y);
      sW2T[(d0 + 4 * i + 2) * W2_STR + k2] = f2bf(v.z);
      sW2T[(d0 + 4 * i + 3) * W2_STR + k2] = f2bf(v.w);
    }
  }
  __syncthreads();
  bf16x8 B2[8];
  {
    const unsigned short* sW2T = (const unsigned short*)pool;
#pragma unroll
    for (int kk = 0; kk < 8; ++kk)
      B2[kk] = *(const bf16x8*)&sW2T[nbase * W2_STR + kk * 16 + lhalf * 8];
  }
  const float b1v = b1[nbase];
  const float b2v = b2[nbase];

  for (int tile = blockIdx.x; tile < NTILES; tile += gridDim.x) {
    const int ebase = tile * TILE_M;
    __syncthreads();

    {
      const int m = t >> 2;
      const int ep = SORTED ? eperm[ebase + m] : (ebase + m);
      const int kq = (t & 3) * 16;
      const float* src = rbf + (size_t)ep * NUM_RBF + kq;
#pragma unroll
      for (int i = 0; i < 4; ++i) {
        float4 v = *(const float4*)(src + 4 * i);
        ushort4 p;
        p.x = f2bf(v.x); p.y = f2bf(v.y); p.z = f2bf(v.z); p.w = f2bf(v.w);
        *(ushort4*)&sRbf[m * RBF_STR + kq + 4 * i] = p;
      }
#pragma unroll
      for (int i = 0; i < 4; ++i) {
        const int chunk = t + 256 * i;
        const int row = chunk >> 4;
        const int c8 = (chunk & 15) * 8;
        const int col = cols[ebase + row];
        *(uint4*)&sHv[row * HV_STR + c8] =
            *(const uint4*)(hbf + (size_t)col * OUT_CH + c8);
      }
      if (t < TILE_M) sAux[t] = dsts[ebase + t];
    }
    __syncthreads();

    float hv[2][16];
#pragma unroll
    for (int mt = 0; mt < 2; ++mt)
#pragma unroll
      for (int r = 0; r < 16; ++r) {
        const int rowm = mt * 32 + (r & 3) + 8 * (r >> 2) + 4 * lhalf;
        hv[mt][r] = bf2f(sHv[rowm * HV_STR + nbase]);
      }
    __syncthreads();

#pragma unroll
    for (int mt = 0; mt < 2; ++mt) {
      f32x16 acc = {0.f, 0.f, 0.f, 0.f, 0.f, 0.f, 0.f, 0.f,
                    0.f, 0.f, 0.f, 0.f, 0.f, 0.f, 0.f, 0.f};
#pragma unroll
      for (int kk = 0; kk < 4; ++kk) {
        bf16x8 A = *(const bf16x8*)&sRbf[(mt * 32 + l31) * RBF_STR + kk * 16 + lhalf * 8];
        acc = __builtin_amdgcn_mfma_f32_32x32x16_bf16(A, B1[kk], acc, 0, 0, 0);
      }
#pragma unroll
      for (int r = 0; r < 16; ++r) {
        const int rowm = (r & 3) + 8 * (r >> 2) + 4 * lhalf;
        float v = acc[r] + b1v;
        v = v > 0.f ? v : 0.f;
        sT[(mt * 32 + rowm) * T_STR + nbase] = f2bf(v);
      }
    }
    __syncthreads();

    float sum = 0.f;
    int curd = -1;
#pragma unroll
    for (int mt = 0; mt < 2; ++mt) {
      f32x16 acc = {0.f, 0.f, 0.f, 0.f, 0.f, 0.f, 0.f, 0.f,
                    0.f, 0.f, 0.f, 0.f, 0.f, 0.f, 0.f, 0.f};
#pragma unroll
      for (int kk = 0; kk < 8; ++kk) {
        bf16x8 A = *(const bf16x8*)&sT[(mt * 32 + l31) * T_STR + kk * 16 + lhalf * 8];
        acc = __builtin_amdgcn_mfma_f32_32x32x16_bf16(A, B2[kk], acc, 0, 0, 0);
      }
#pragma unroll
      for (int r = 0; r < 16; ++r) {
        const int rowm = mt * 32 + (r & 3) + 8 * (r >> 2) + 4 * lhalf;
        const float m = hv[mt][r] * (acc[r] + b2v);
        const int d = SORTED ? sAux[rowm] : dsts[ebase + rowm];
        if (d != curd) {
          if (curd >= 0) atomicAdd(&outp[(size_t)curd * OUT_CH + nbase], sum);
          curd = d;
          sum = m;
        } else {
          sum += m;
        }
      }
    }
    atomicAdd(&outp[(size_t)curd * OUT_CH + nbase], sum);
  }
}

// ---------------------------------------------------------------------------
extern "C" void kernel_launch(void* const* d_in, const int* in_sizes, int n_in,
                              void* d_out, int out_size, void* d_ws, size_t ws_size,
                              hipStream_t stream) {
  const float* x    = (const float*)d_in[0];
  const int*   eidx = (const int*)d_in[1];
  const float* rbf  = (const float*)d_in[2];
  const float* W1   = (const float*)d_in[3];
  const float* b1   = (const float*)d_in[4];
  const float* W2   = (const float*)d_in[5];
  const float* b2   = (const float*)d_in[6];
  const float* Wl   = (const float*)d_in[7];
  const float* bl   = (const float*)d_in[8];
  float* out = (float*)d_out;

  char* ws = (char*)d_ws;
  const size_t HBF_B = (size_t)N_NODES * OUT_CH * 2;  // 10,240,000
  const size_t EP_B = (size_t)N_EDGES * 4;            //  2,560,000 (x3)
  const size_t CNT_B = (size_t)N_NODES * 4;           //    160,000 (x3)
  const size_t BS_B = 4 * 256;
  const size_t need = HBF_B + 3 * EP_B + 3 * CNT_B + 2 * BS_B + 64;

  size_t off = 0;
  unsigned short* hbf = (unsigned short*)(ws + off); off += HBF_B;
  int* eperm  = (int*)(ws + off); off += EP_B;
  int* dsts   = (int*)(ws + off); off += EP_B;
  int* cols   = (int*)(ws + off); off += EP_B;
  int* count  = (int*)(ws + off); off += CNT_B;
  int* cursor = (int*)(ws + off); off += CNT_B;
  int* tscan  = (int*)(ws + off); off += CNT_B;
  int* bsum   = (int*)(ws + off); off += BS_B;
  int* boff   = (int*)(ws + off); off += BS_B;

  const int* rowI = eidx;
  const int* colI = eidx + N_EDGES;

  if (ws_size >= need) {
    void* kargs[] = {(void*)&x,     (void*)&eidx, (void*)&rbf,   (void*)&W1,
                     (void*)&b1,    (void*)&W2,   (void*)&b2,    (void*)&Wl,
                     (void*)&bl,    (void*)&hbf,  (void*)&eperm, (void*)&dsts,
                     (void*)&cols,  (void*)&count, (void*)&cursor,
                     (void*)&tscan, (void*)&bsum, (void*)&boff,  (void*)&out};
    hipError_t err = hipLaunchCooperativeKernel(
        mega_kernel, dim3(EDGE_GRID), dim3(256), kargs, 0, stream);
    if (err == hipSuccess) return;
    (void)hipGetLastError();  // clear and fall through to multi-kernel path

    hipMemsetAsync(out, 0, (size_t)N_NODES * OUT_CH * sizeof(float), stream);
    node_linear_mfma<<<NB_NODE, 256, 0, stream>>>(x, Wl, bl, hbf);
    hipMemsetAsync(count, 0, CNT_B, stream);
    hist_kernel<<<(N_EDGES + 255) / 256, 256, 0, stream>>>(rowI, count);
    scan1_kernel<<<NSCB, 256, 0, stream>>>(count, tscan, bsum);
    scan2_kernel<<<1, 256, 0, stream>>>(bsum, boff);
    scan3_kernel<<<NSCB, 256, 0, stream>>>(count, tscan, boff, cursor);
    scatter_kernel<<<(N_EDGES + 255) / 256, 256, 0, stream>>>(
        rowI, colI, cursor, eperm, dsts, cols);
    edge_fused_kernel<true><<<EDGE_GRID, 256, 0, stream>>>(
        eperm, rbf, W1, b1, W2, b2, hbf, dsts, cols, out);
  } else {
    hipMemsetAsync(out, 0, (size_t)N_NODES * OUT_CH * sizeof(float), stream);
    node_linear_mfma<<<NB_NODE, 256, 0, stream>>>(x, Wl, bl, hbf);
    edge_fused_kernel<false><<<EDGE_GRID, 256, 0, stream>>>(
        nullptr, rbf, W1, b1, W2, b2, hbf, rowI, colI, out);
  }
}

// Round 3
// 496.602 us; speedup vs baseline: 2.8801x; 2.8801x over previous
//
#include <hip/hip_runtime.h>

// CFConv, round 7. Lessons: grid.sync() costs ~150us/sync on MI355X -> banned.
// Multi-kernel pipeline, stream-ordered fusion instead:
//  K1: node_linear (blocks 0-624) | zero count (625-656) | zero out (657-1023)
//  K2: hist (atomic count) + zero scan-status (block 0)
//  K3: single-dispatch decoupled-lookback scan -> cursor
//  K4: scatter -> packed u64 (dst<<36 | col<<20 | e)
//  K5: edge_fused with T14 async-stage split (prefetch next tile into regs,
//      HBM latency hides under GEMM1+GEMM2)

#define N_NODES 40000
#define N_EDGES 640000
#define IN_CH 128
#define OUT_CH 128
#define NUM_RBF 64

#define TILE_M 64
#define NTILES (N_EDGES / TILE_M)   // 10000
#define NB_NODE (N_NODES / TILE_M)  // 625
#define RBF_STR 72   // ushorts
#define T_STR 136    // ushorts
#define HV_STR 136   // ushorts
#define W1_STR 72
#define W2_STR 136
#define NSCB ((N_NODES + 255) / 256)  // 157
#define EDGE_GRID 1024
#define K1_GRID 1024
#define ZC_BLOCKS 32

typedef __attribute__((ext_vector_type(8))) short bf16x8;
typedef __attribute__((ext_vector_type(16))) float f32x16;

__device__ __forceinline__ unsigned short f2bf(float f) {
  unsigned u = __float_as_uint(f);
  return (unsigned short)((u + 0x7FFFu + ((u >> 16) & 1u)) >> 16);
}
__device__ __forceinline__ float bf2f(unsigned short s) {
  return __uint_as_float(((unsigned)s) << 16);
}

// ---------------------------------------------------------------------------
// K1: node_linear | zero(count) | zero(out)   (disjoint block ranges)
// ---------------------------------------------------------------------------
__global__ __launch_bounds__(256) void k1_kernel(
    const float* __restrict__ x, const float* __restrict__ Wl,
    const float* __restrict__ bl, unsigned short* __restrict__ hbf,
    int* __restrict__ count, float* __restrict__ outp) {
  __shared__ __align__(16) char pool[IN_CH * W2_STR * 2];  // 34816 B
  const int bid = blockIdx.x;
  const int t = threadIdx.x;

  if (bid >= NB_NODE) {
    if (bid < NB_NODE + ZC_BLOCKS) {
      if (count) {
        int4 z = {0, 0, 0, 0};
        for (int i = (bid - NB_NODE) * 256 + t; i < N_NODES / 4;
             i += ZC_BLOCKS * 256)
          ((int4*)count)[i] = z;
      }
    } else {
      if (outp) {
        float4 z = {0.f, 0.f, 0.f, 0.f};
        const int nb = K1_GRID - NB_NODE - ZC_BLOCKS;
        for (int i = (bid - NB_NODE - ZC_BLOCKS) * 256 + t;
             i < N_NODES * OUT_CH / 4; i += nb * 256)
          ((float4*)outp)[i] = z;
      }
    }
    return;
  }

  const int lane = t & 63;
  const int l31 = lane & 31;
  const int lhalf = lane >> 5;
  const int wv = t >> 6;
  const int nbase = wv * 32 + l31;

  {
    unsigned short* sWT = (unsigned short*)pool;
    const int k2 = t >> 1;
    const int d0 = (t & 1) * 64;
#pragma unroll
    for (int i = 0; i < 16; ++i) {
      float4 v = *(const float4*)(Wl + k2 * OUT_CH + d0 + 4 * i);
      sWT[(d0 + 4 * i + 0) * W2_STR + k2] = f2bf(v.x);
      sWT[(d0 + 4 * i + 1) * W2_STR + k2] = f2bf(v.y);
      sWT[(d0 + 4 * i + 2) * W2_STR + k2] = f2bf(v.z);
      sWT[(d0 + 4 * i + 3) * W2_STR + k2] = f2bf(v.w);
    }
  }
  __syncthreads();
  bf16x8 BW[8];
  {
    const unsigned short* sWT = (const unsigned short*)pool;
#pragma unroll
    for (int kk = 0; kk < 8; ++kk)
      BW[kk] = *(const bf16x8*)&sWT[nbase * W2_STR + kk * 16 + lhalf * 8];
  }
  const float blv = bl[nbase];
  __syncthreads();

  const int rbase = bid * TILE_M;
  unsigned short* sX = (unsigned short*)pool;
  {
    const int m = t >> 2;
    const int c0 = (t & 3) * 32;
    const float* src = x + (size_t)(rbase + m) * IN_CH + c0;
#pragma unroll
    for (int i = 0; i < 8; ++i) {
      float4 v = *(const float4*)(src + 4 * i);
      ushort4 p;
      p.x = f2bf(v.x); p.y = f2bf(v.y); p.z = f2bf(v.z); p.w = f2bf(v.w);
      *(ushort4*)&sX[m * T_STR + c0 + 4 * i] = p;
    }
  }
  __syncthreads();
#pragma unroll
  for (int mt = 0; mt < 2; ++mt) {
    f32x16 acc = {0.f, 0.f, 0.f, 0.f, 0.f, 0.f, 0.f, 0.f,
                  0.f, 0.f, 0.f, 0.f, 0.f, 0.f, 0.f, 0.f};
#pragma unroll
    for (int kk = 0; kk < 8; ++kk) {
      bf16x8 A = *(const bf16x8*)&sX[(mt * 32 + l31) * T_STR + kk * 16 + lhalf * 8];
      acc = __builtin_amdgcn_mfma_f32_32x32x16_bf16(A, BW[kk], acc, 0, 0, 0);
    }
#pragma unroll
    for (int r = 0; r < 16; ++r) {
      const int rowm = mt * 32 + (r & 3) + 8 * (r >> 2) + 4 * lhalf;
      hbf[(size_t)(rbase + rowm) * OUT_CH + nbase] = f2bf(acc[r] + blv);
    }
  }
}

// ---------------------------------------------------------------------------
// K2: histogram of dst + zero scan-status
// ---------------------------------------------------------------------------
__global__ void hist_kernel(const int* __restrict__ rowI, int* __restrict__ count,
                            unsigned long long* __restrict__ status) {
  if (blockIdx.x == 0 && threadIdx.x < NSCB) status[threadIdx.x] = 0ULL;
  int e = blockIdx.x * 256 + threadIdx.x;
  if (e < N_EDGES) atomicAdd(&count[rowI[e]], 1);
}

// ---------------------------------------------------------------------------
// K3: single-dispatch decoupled-lookback exclusive scan -> cursor
// 157 blocks, all resident; block b spins only on lower block ids.
// ---------------------------------------------------------------------------
__global__ __launch_bounds__(256) void scan_kernel(
    const int* __restrict__ count, unsigned long long* __restrict__ status,
    int* __restrict__ cursor) {
  __shared__ int s[256];
  __shared__ int wsum[4];
  const int t = threadIdx.x;
  const int b = blockIdx.x;
  const int i = b * 256 + t;
  const int v = (i < N_NODES) ? count[i] : 0;
  s[t] = v;
  __syncthreads();
  for (int off = 1; off < 256; off <<= 1) {
    int u = (t >= off) ? s[t - off] : 0;
    __syncthreads();
    s[t] += u;
    __syncthreads();
  }
  if (t == 255)
    __hip_atomic_store(&status[b], (1ULL << 32) | (unsigned)s[255],
                       __ATOMIC_RELEASE, __HIP_MEMORY_SCOPE_AGENT);
  int contrib = 0;
  if (t < b) {  // b <= 156 < 255: one predecessor per thread
    unsigned long long sv;
    do {
      sv = __hip_atomic_load(&status[t], __ATOMIC_ACQUIRE,
                             __HIP_MEMORY_SCOPE_AGENT);
    } while (!(sv >> 32));
    contrib = (int)(unsigned)sv;
  }
  for (int o = 32; o > 0; o >>= 1) contrib += __shfl_down(contrib, o, 64);
  if ((t & 63) == 0) wsum[t >> 6] = contrib;
  __syncthreads();
  const int boffv = wsum[0] + wsum[1] + wsum[2] + wsum[3];
  if (i < N_NODES) cursor[i] = boffv + s[t] - v;
}

// ---------------------------------------------------------------------------
// K4: scatter -> packed u64: dst[51:36] | col[35:20] | e[19:0]
// ---------------------------------------------------------------------------
__global__ void scatter_kernel(const int* __restrict__ rowI,
                               const int* __restrict__ colI,
                               int* __restrict__ cursor,
                               unsigned long long* __restrict__ packed) {
  int e = blockIdx.x * 256 + threadIdx.x;
  if (e < N_EDGES) {
    const int r = rowI[e];
    const int c = colI[e];
    const int p = atomicAdd(&cursor[r], 1);
    packed[p] = ((unsigned long long)r << 36) | ((unsigned long long)c << 20) |
                (unsigned)e;
  }
}

// ---------------------------------------------------------------------------
// K5: fused filter + modulate + segmented reduce, sorted order,
//     T14 async-stage prefetch (next tile's rbf/hbf loads issued one tile
//     ahead; latency hides under GEMM1+GEMM2).
// ---------------------------------------------------------------------------
__global__ __launch_bounds__(256, 4) void edge_fused_kernel(
    const unsigned long long* __restrict__ packed, const float* __restrict__ rbf,
    const float* __restrict__ W1, const float* __restrict__ b1,
    const float* __restrict__ W2, const float* __restrict__ b2,
    const unsigned short* __restrict__ hbf, float* __restrict__ outp) {
  __shared__ __align__(16) char pool[IN_CH * W2_STR * 2];  // 34816 B

  unsigned short* sHv = (unsigned short*)pool;                            // 17408
  unsigned short* sT = (unsigned short*)pool;                             // overlap
  unsigned short* sRbf = (unsigned short*)(pool + TILE_M * HV_STR * 2);   // 9216
  int* sAux = (int*)(pool + TILE_M * HV_STR * 2 + TILE_M * RBF_STR * 2);  // 256

  const int t = threadIdx.x;
  const int lane = t & 63;
  const int l31 = lane & 31;
  const int lhalf = lane >> 5;
  const int wv = t >> 6;
  const int nbase = wv * 32 + l31;

  // ---- weight fragments (pool reused twice) ----
  {
    unsigned short* sW1T = (unsigned short*)pool;
    const int k = t >> 2;
    const int c0 = (t & 3) * 32;
#pragma unroll
    for (int i = 0; i < 8; ++i) {
      float4 v = *(const float4*)(W1 + k * OUT_CH + c0 + 4 * i);
      sW1T[(c0 + 4 * i + 0) * W1_STR + k] = f2bf(v.x);
      sW1T[(c0 + 4 * i + 1) * W1_STR + k] = f2bf(v.y);
      sW1T[(c0 + 4 * i + 2) * W1_STR + k] = f2bf(v.z);
      sW1T[(c0 + 4 * i + 3) * W1_STR + k] = f2bf(v.w);
    }
  }
  __syncthreads();
  bf16x8 B1[4];
  {
    const unsigned short* sW1T = (const unsigned short*)pool;
#pragma unroll
    for (int kk = 0; kk < 4; ++kk)
      B1[kk] = *(const bf16x8*)&sW1T[nbase * W1_STR + kk * 16 + lhalf * 8];
  }
  __syncthreads();
  {
    unsigned short* sW2T = (unsigned short*)pool;
    const int k2 = t >> 1;
    const int d0 = (t & 1) * 64;
#pragma unroll
    for (int i = 0; i < 16; ++i) {
      float4 v = *(const float4*)(W2 + k2 * OUT_CH + d0 + 4 * i);
      sW2T[(d0 + 4 * i + 0) * W2_STR + k2] = f2bf(v.x);
      sW2T[(d0 + 4 * i + 1) * W2_STR + k2] = f2bf(v.y);
      sW2T[(d0 + 4 * i + 2) * W2_STR + k2] = f2bf(v.z);
      sW2T[(d0 + 4 * i + 3) * W2_STR + k2] = f2bf(v.w);
    }
  }
  __syncthreads();
  bf16x8 B2[8];
  {
    const unsigned short* sW2T = (const unsigned short*)pool;
#pragma unroll
    for (int kk = 0; kk < 8; ++kk)
      B2[kk] = *(const bf16x8*)&sW2T[nbase * W2_STR + kk * 16 + lhalf * 8];
  }
  const float b1v = b1[nbase];
  const float b2v = b2[nbase];

  const int m4 = t >> 2;        // rbf row this thread stages
  const int kq = (t & 3) * 16;  // rbf col quarter

  float4 rbfreg[4];
  uint4 hvreg[4];
  int auxv = 0;

  auto prefetch = [&](int tl) {
    const int eb = tl * TILE_M;
    const unsigned long long pkm = packed[eb + m4];
    const float* src = rbf + (size_t)(pkm & 0xFFFFFu) * NUM_RBF + kq;
#pragma unroll
    for (int i = 0; i < 4; ++i) rbfreg[i] = *(const float4*)(src + 4 * i);
#pragma unroll
    for (int i = 0; i < 4; ++i) {
      const int chunk = t + 256 * i;
      const int row = chunk >> 4;
      const int c8 = (chunk & 15) * 8;
      const unsigned long long pkr = packed[eb + row];
      const int col = (int)((pkr >> 20) & 0xFFFFu);
      hvreg[i] = *(const uint4*)(hbf + (size_t)col * OUT_CH + c8);
    }
    if (t < TILE_M) auxv = (int)(packed[eb + t] >> 36);
  };

  int tile = blockIdx.x;
  if (tile < NTILES) prefetch(tile);

  for (; tile < NTILES; tile += gridDim.x) {
    __syncthreads();  // (a) prev GEMM2's sT/sAux reads complete

    // ---- store staged regs -> LDS ----
#pragma unroll
    for (int i = 0; i < 4; ++i) {
      float4 v = rbfreg[i];
      ushort4 p;
      p.x = f2bf(v.x); p.y = f2bf(v.y); p.z = f2bf(v.z); p.w = f2bf(v.w);
      *(ushort4*)&sRbf[m4 * RBF_STR + kq + 4 * i] = p;
    }
#pragma unroll
    for (int i = 0; i < 4; ++i) {
      const int chunk = t + 256 * i;
      const int row = chunk >> 4;
      const int c8 = (chunk & 15) * 8;
      *(uint4*)&sHv[row * HV_STR + c8] = hvreg[i];
    }
    if (t < TILE_M) sAux[t] = auxv;
    __syncthreads();  // (b)

    // ---- prefetch next tile (covers hv read + GEMM1 + GEMM2) ----
    const int tn = tile + gridDim.x;
    if (tn < NTILES) prefetch(tn);

    // ---- h values from LDS (before sT overwrites sHv) ----
    float hv[2][16];
#pragma unroll
    for (int mt = 0; mt < 2; ++mt)
#pragma unroll
      for (int r = 0; r < 16; ++r) {
        const int rowm = mt * 32 + (r & 3) + 8 * (r >> 2) + 4 * lhalf;
        hv[mt][r] = bf2f(sHv[rowm * HV_STR + nbase]);
      }
    __syncthreads();  // (b2) sHv dead; sT may overwrite

    // ---- GEMM1: sT = bf16(relu(rbf @ W1 + b1)) ----
#pragma unroll
    for (int mt = 0; mt < 2; ++mt) {
      f32x16 acc = {0.f, 0.f, 0.f, 0.f, 0.f, 0.f, 0.f, 0.f,
                    0.f, 0.f, 0.f, 0.f, 0.f, 0.f, 0.f, 0.f};
#pragma unroll
      for (int kk = 0; kk < 4; ++kk) {
        bf16x8 A = *(const bf16x8*)&sRbf[(mt * 32 + l31) * RBF_STR + kk * 16 + lhalf * 8];
        acc = __builtin_amdgcn_mfma_f32_32x32x16_bf16(A, B1[kk], acc, 0, 0, 0);
      }
#pragma unroll
      for (int r = 0; r < 16; ++r) {
        const int rowm = (r & 3) + 8 * (r >> 2) + 4 * lhalf;
        float v = acc[r] + b1v;
        v = v > 0.f ? v : 0.f;
        sT[(mt * 32 + rowm) * T_STR + nbase] = f2bf(v);
      }
    }
    __syncthreads();  // (c)

    // ---- GEMM2 + modulate + in-register segmented reduce ----
    float sum = 0.f;
    int curd = -1;
#pragma unroll
    for (int mt = 0; mt < 2; ++mt) {
      f32x16 acc = {0.f, 0.f, 0.f, 0.f, 0.f, 0.f, 0.f, 0.f,
                    0.f, 0.f, 0.f, 0.f, 0.f, 0.f, 0.f, 0.f};
#pragma unroll
      for (int kk = 0; kk < 8; ++kk) {
        bf16x8 A = *(const bf16x8*)&sT[(mt * 32 + l31) * T_STR + kk * 16 + lhalf * 8];
        acc = __builtin_amdgcn_mfma_f32_32x32x16_bf16(A, B2[kk], acc, 0, 0, 0);
      }
#pragma unroll
      for (int r = 0; r < 16; ++r) {
        const int rowm = mt * 32 + (r & 3) + 8 * (r >> 2) + 4 * lhalf;
        const float m = hv[mt][r] * (acc[r] + b2v);
        const int d = sAux[rowm];
        if (d != curd) {
          if (curd >= 0) atomicAdd(&outp[(size_t)curd * OUT_CH + nbase], sum);
          curd = d;
          sum = m;
        } else {
          sum += m;
        }
      }
    }
    atomicAdd(&outp[(size_t)curd * OUT_CH + nbase], sum);
  }
}

// ---------------------------------------------------------------------------
// Fallback: natural-order edge kernel, atomic per row (ws too small)
// ---------------------------------------------------------------------------
__global__ __launch_bounds__(256, 4) void edge_atomic_kernel(
    const int* __restrict__ eidx, const float* __restrict__ rbf,
    const float* __restrict__ W1, const float* __restrict__ b1,
    const float* __restrict__ W2, const float* __restrict__ b2,
    const unsigned short* __restrict__ hbf, float* __restrict__ outp) {
  __shared__ __align__(16) char pool[IN_CH * W2_STR * 2];

  unsigned short* sHv = (unsigned short*)pool;
  unsigned short* sT = (unsigned short*)pool;
  unsigned short* sRbf = (unsigned short*)(pool + TILE_M * HV_STR * 2);
  int* sAux = (int*)(pool + TILE_M * HV_STR * 2 + TILE_M * RBF_STR * 2);

  const int t = threadIdx.x;
  const int lane = t & 63;
  const int l31 = lane & 31;
  const int lhalf = lane >> 5;
  const int wv = t >> 6;
  const int nbase = wv * 32 + l31;

  {
    unsigned short* sW1T = (unsigned short*)pool;
    const int k = t >> 2;
    const int c0 = (t & 3) * 32;
#pragma unroll
    for (int i = 0; i < 8; ++i) {
      float4 v = *(const float4*)(W1 + k * OUT_CH + c0 + 4 * i);
      sW1T[(c0 + 4 * i + 0) * W1_STR + k] = f2bf(v.x);
      sW1T[(c0 + 4 * i + 1) * W1_STR + k] = f2bf(v.y);
      sW1T[(c0 + 4 * i + 2) * W1_STR + k] = f2bf(v.z);
      sW1T[(c0 + 4 * i + 3) * W1_STR + k] = f2bf(v.w);
    }
  }
  __syncthreads();
  bf16x8 B1[4];
  {
    const unsigned short* sW1T = (const unsigned short*)pool;
#pragma unroll
    for (int kk = 0; kk < 4; ++kk)
      B1[kk] = *(const bf16x8*)&sW1T[nbase * W1_STR + kk * 16 + lhalf * 8];
  }
  __syncthreads();
  {
    unsigned short* sW2T = (unsigned short*)pool;
    const int k2 = t >> 1;
    const int d0 = (t & 1) * 64;
#pragma unroll
    for (int i = 0; i < 16; ++i) {
      float4 v = *(const float4*)(W2 + k2 * OUT_CH + d0 + 4 * i);
      sW2T[(d0 + 4 * i + 0) * W2_STR + k2] = f2bf(v.x);
      sW2T[(d0 + 4 * i + 1) * W2_STR + k2] = f2bf(v.y);
      sW2T[(d0 + 4 * i + 2) * W2_STR + k2] = f2bf(v.z);
      sW2T[(d0 + 4 * i + 3) * W2_STR + k2] = f2bf(v.w);
    }
  }
  __syncthreads();
  bf16x8 B2[8];
  {
    const unsigned short* sW2T = (const unsigned short*)pool;
#pragma unroll
    for (int kk = 0; kk < 8; ++kk)
      B2[kk] = *(const bf16x8*)&sW2T[nbase * W2_STR + kk * 16 + lhalf * 8];
  }
  const float b1v = b1[nbase];
  const float b2v = b2[nbase];

  const int* rowI = eidx;
  const int* colI = eidx + N_EDGES;

  for (int tile = blockIdx.x; tile < NTILES; tile += gridDim.x) {
    const int ebase = tile * TILE_M;
    __syncthreads();
    {
      const int m = t >> 2;
      const int kq = (t & 3) * 16;
      const float* src = rbf + (size_t)(ebase + m) * NUM_RBF + kq;
#pragma unroll
      for (int i = 0; i < 4; ++i) {
        float4 v = *(const float4*)(src + 4 * i);
        ushort4 p;
        p.x = f2bf(v.x); p.y = f2bf(v.y); p.z = f2bf(v.z); p.w = f2bf(v.w);
        *(ushort4*)&sRbf[m * RBF_STR + kq + 4 * i] = p;
      }
#pragma unroll
      for (int i = 0; i < 4; ++i) {
        const int chunk = t + 256 * i;
        const int row = chunk >> 4;
        const int c8 = (chunk & 15) * 8;
        const int col = colI[ebase + row];
        *(uint4*)&sHv[row * HV_STR + c8] =
            *(const uint4*)(hbf + (size_t)col * OUT_CH + c8);
      }
      if (t < TILE_M) sAux[t] = rowI[ebase + t];
    }
    __syncthreads();

    float hv[2][16];
#pragma unroll
    for (int mt = 0; mt < 2; ++mt)
#pragma unroll
      for (int r = 0; r < 16; ++r) {
        const int rowm = mt * 32 + (r & 3) + 8 * (r >> 2) + 4 * lhalf;
        hv[mt][r] = bf2f(sHv[rowm * HV_STR + nbase]);
      }
    __syncthreads();

#pragma unroll
    for (int mt = 0; mt < 2; ++mt) {
      f32x16 acc = {0.f, 0.f, 0.f, 0.f, 0.f, 0.f, 0.f, 0.f,
                    0.f, 0.f, 0.f, 0.f, 0.f, 0.f, 0.f, 0.f};
#pragma unroll
      for (int kk = 0; kk < 4; ++kk) {
        bf16x8 A = *(const bf16x8*)&sRbf[(mt * 32 + l31) * RBF_STR + kk * 16 + lhalf * 8];
        acc = __builtin_amdgcn_mfma_f32_32x32x16_bf16(A, B1[kk], acc, 0, 0, 0);
      }
#pragma unroll
      for (int r = 0; r < 16; ++r) {
        const int rowm = (r & 3) + 8 * (r >> 2) + 4 * lhalf;
        float v = acc[r] + b1v;
        v = v > 0.f ? v : 0.f;
        sT[(mt * 32 + rowm) * T_STR + nbase] = f2bf(v);
      }
    }
    __syncthreads();

    float sum = 0.f;
    int curd = -1;
#pragma unroll
    for (int mt = 0; mt < 2; ++mt) {
      f32x16 acc = {0.f, 0.f, 0.f, 0.f, 0.f, 0.f, 0.f, 0.f,
                    0.f, 0.f, 0.f, 0.f, 0.f, 0.f, 0.f, 0.f};
#pragma unroll
      for (int kk = 0; kk < 8; ++kk) {
        bf16x8 A = *(const bf16x8*)&sT[(mt * 32 + l31) * T_STR + kk * 16 + lhalf * 8];
        acc = __builtin_amdgcn_mfma_f32_32x32x16_bf16(A, B2[kk], acc, 0, 0, 0);
      }
#pragma unroll
      for (int r = 0; r < 16; ++r) {
        const int rowm = mt * 32 + (r & 3) + 8 * (r >> 2) + 4 * lhalf;
        const float m = hv[mt][r] * (acc[r] + b2v);
        const int d = sAux[rowm];
        if (d != curd) {
          if (curd >= 0) atomicAdd(&outp[(size_t)curd * OUT_CH + nbase], sum);
          curd = d;
          sum = m;
        } else {
          sum += m;
        }
      }
    }
    atomicAdd(&outp[(size_t)curd * OUT_CH + nbase], sum);
  }
}

// ---------------------------------------------------------------------------
extern "C" void kernel_launch(void* const* d_in, const int* in_sizes, int n_in,
                              void* d_out, int out_size, void* d_ws, size_t ws_size,
                              hipStream_t stream) {
  const float* x    = (const float*)d_in[0];
  const int*   eidx = (const int*)d_in[1];
  const float* rbf  = (const float*)d_in[2];
  const float* W1   = (const float*)d_in[3];
  const float* b1   = (const float*)d_in[4];
  const float* W2   = (const float*)d_in[5];
  const float* b2   = (const float*)d_in[6];
  const float* Wl   = (const float*)d_in[7];
  const float* bl   = (const float*)d_in[8];
  float* out = (float*)d_out;

  char* ws = (char*)d_ws;
  const size_t HBF_B = (size_t)N_NODES * OUT_CH * 2;   // 10,240,000
  const size_t PK_B = (size_t)N_EDGES * 8;             //  5,120,000
  const size_t CNT_B = (size_t)N_NODES * 4;            //    160,000 (x2)
  const size_t ST_B = 1280;
  const size_t need = HBF_B + PK_B + 2 * CNT_B + ST_B + 64;

  size_t off = 0;
  unsigned short* hbf = (unsigned short*)(ws + off); off += HBF_B;
  unsigned long long* packed = (unsigned long long*)(ws + off); off += PK_B;
  int* count  = (int*)(ws + off); off += CNT_B;
  int* cursor = (int*)(ws + off); off += CNT_B;
  unsigned long long* status = (unsigned long long*)(ws + off); off += ST_B;

  const int* rowI = eidx;
  const int* colI = eidx + N_EDGES;

  if (ws_size >= need) {
    k1_kernel<<<K1_GRID, 256, 0, stream>>>(x, Wl, bl, hbf, count, out);
    hist_kernel<<<(N_EDGES + 255) / 256, 256, 0, stream>>>(rowI, count, status);
    scan_kernel<<<NSCB, 256, 0, stream>>>(count, status, cursor);
    scatter_kernel<<<(N_EDGES + 255) / 256, 256, 0, stream>>>(
        rowI, colI, cursor, packed);
    edge_fused_kernel<<<EDGE_GRID, 256, 0, stream>>>(
        packed, rbf, W1, b1, W2, b2, hbf, out);
  } else {
    hipMemsetAsync(out, 0, (size_t)N_NODES * OUT_CH * sizeof(float), stream);
    k1_kernel<<<NB_NODE, 256, 0, stream>>>(x, Wl, bl, hbf, nullptr, nullptr);
    edge_atomic_kernel<<<EDGE_GRID, 256, 0, stream>>>(
        eidx, rbf, W1, b1, W2, b2, hbf, out);
  }
}

// Round 4
// 418.841 us; speedup vs baseline: 3.4148x; 1.1857x over previous
//
#include <hip/hip_runtime.h>

// CFConv, round 8. Round-7 pipeline, prefetch spill fixed:
//  - round-7's prefetch lambda captured local arrays by reference -> scratch
//    (+300MB HBM round-trip). Rebuilt with NAMED SCALARS (rb0..3, hq0..3) and
//    __launch_bounds__(256,3) so the ~140-reg demand fits without spilling.
//  K1: node_linear | zero(count) | zero(out)   (block-range split)
//  K2: hist + zero scan-status
//  K3: decoupled-lookback scan -> cursor
//  K4: scatter -> packed u64 (dst<<36 | col<<20 | e)
//  K5: edge_fused, dst-sorted, T14 prefetch (named regs), segmented reduce

#define N_NODES 40000
#define N_EDGES 640000
#define IN_CH 128
#define OUT_CH 128
#define NUM_RBF 64

#define TILE_M 64
#define NTILES (N_EDGES / TILE_M)   // 10000
#define NB_NODE (N_NODES / TILE_M)  // 625
#define RBF_STR 72   // ushorts
#define T_STR 136    // ushorts
#define HV_STR 136   // ushorts
#define W1_STR 72
#define W2_STR 136
#define NSCB ((N_NODES + 255) / 256)  // 157
#define EDGE_GRID 1024
#define K1_GRID 1024
#define ZC_BLOCKS 32

typedef __attribute__((ext_vector_type(8))) short bf16x8;
typedef __attribute__((ext_vector_type(16))) float f32x16;

__device__ __forceinline__ unsigned short f2bf(float f) {
  unsigned u = __float_as_uint(f);
  return (unsigned short)((u + 0x7FFFu + ((u >> 16) & 1u)) >> 16);
}
__device__ __forceinline__ float bf2f(unsigned short s) {
  return __uint_as_float(((unsigned)s) << 16);
}

// ---------------------------------------------------------------------------
// K1: node_linear | zero(count) | zero(out)   (disjoint block ranges)
// ---------------------------------------------------------------------------
__global__ __launch_bounds__(256) void k1_kernel(
    const float* __restrict__ x, const float* __restrict__ Wl,
    const float* __restrict__ bl, unsigned short* __restrict__ hbf,
    int* __restrict__ count, float* __restrict__ outp) {
  __shared__ __align__(16) char pool[IN_CH * W2_STR * 2];  // 34816 B
  const int bid = blockIdx.x;
  const int t = threadIdx.x;

  if (bid >= NB_NODE) {
    if (bid < NB_NODE + ZC_BLOCKS) {
      if (count) {
        int4 z = {0, 0, 0, 0};
        for (int i = (bid - NB_NODE) * 256 + t; i < N_NODES / 4;
             i += ZC_BLOCKS * 256)
          ((int4*)count)[i] = z;
      }
    } else {
      if (outp) {
        float4 z = {0.f, 0.f, 0.f, 0.f};
        const int nb = K1_GRID - NB_NODE - ZC_BLOCKS;
        for (int i = (bid - NB_NODE - ZC_BLOCKS) * 256 + t;
             i < N_NODES * OUT_CH / 4; i += nb * 256)
          ((float4*)outp)[i] = z;
      }
    }
    return;
  }

  const int lane = t & 63;
  const int l31 = lane & 31;
  const int lhalf = lane >> 5;
  const int wv = t >> 6;
  const int nbase = wv * 32 + l31;

  {
    unsigned short* sWT = (unsigned short*)pool;
    const int k2 = t >> 1;
    const int d0 = (t & 1) * 64;
#pragma unroll
    for (int i = 0; i < 16; ++i) {
      float4 v = *(const float4*)(Wl + k2 * OUT_CH + d0 + 4 * i);
      sWT[(d0 + 4 * i + 0) * W2_STR + k2] = f2bf(v.x);
      sWT[(d0 + 4 * i + 1) * W2_STR + k2] = f2bf(v.y);
      sWT[(d0 + 4 * i + 2) * W2_STR + k2] = f2bf(v.z);
      sWT[(d0 + 4 * i + 3) * W2_STR + k2] = f2bf(v.w);
    }
  }
  __syncthreads();
  bf16x8 BW[8];
  {
    const unsigned short* sWT = (const unsigned short*)pool;
#pragma unroll
    for (int kk = 0; kk < 8; ++kk)
      BW[kk] = *(const bf16x8*)&sWT[nbase * W2_STR + kk * 16 + lhalf * 8];
  }
  const float blv = bl[nbase];
  __syncthreads();

  const int rbase = bid * TILE_M;
  unsigned short* sX = (unsigned short*)pool;
  {
    const int m = t >> 2;
    const int c0 = (t & 3) * 32;
    const float* src = x + (size_t)(rbase + m) * IN_CH + c0;
#pragma unroll
    for (int i = 0; i < 8; ++i) {
      float4 v = *(const float4*)(src + 4 * i);
      ushort4 p;
      p.x = f2bf(v.x); p.y = f2bf(v.y); p.z = f2bf(v.z); p.w = f2bf(v.w);
      *(ushort4*)&sX[m * T_STR + c0 + 4 * i] = p;
    }
  }
  __syncthreads();
#pragma unroll
  for (int mt = 0; mt < 2; ++mt) {
    f32x16 acc = {0.f, 0.f, 0.f, 0.f, 0.f, 0.f, 0.f, 0.f,
                  0.f, 0.f, 0.f, 0.f, 0.f, 0.f, 0.f, 0.f};
#pragma unroll
    for (int kk = 0; kk < 8; ++kk) {
      bf16x8 A = *(const bf16x8*)&sX[(mt * 32 + l31) * T_STR + kk * 16 + lhalf * 8];
      acc = __builtin_amdgcn_mfma_f32_32x32x16_bf16(A, BW[kk], acc, 0, 0, 0);
    }
#pragma unroll
    for (int r = 0; r < 16; ++r) {
      const int rowm = mt * 32 + (r & 3) + 8 * (r >> 2) + 4 * lhalf;
      hbf[(size_t)(rbase + rowm) * OUT_CH + nbase] = f2bf(acc[r] + blv);
    }
  }
}

// ---------------------------------------------------------------------------
// K2: histogram of dst + zero scan-status
// ---------------------------------------------------------------------------
__global__ void hist_kernel(const int* __restrict__ rowI, int* __restrict__ count,
                            unsigned long long* __restrict__ status) {
  if (blockIdx.x == 0 && threadIdx.x < NSCB) status[threadIdx.x] = 0ULL;
  int e = blockIdx.x * 256 + threadIdx.x;
  if (e < N_EDGES) atomicAdd(&count[rowI[e]], 1);
}

// ---------------------------------------------------------------------------
// K3: single-dispatch decoupled-lookback exclusive scan -> cursor
// ---------------------------------------------------------------------------
__global__ __launch_bounds__(256) void scan_kernel(
    const int* __restrict__ count, unsigned long long* __restrict__ status,
    int* __restrict__ cursor) {
  __shared__ int s[256];
  __shared__ int wsum[4];
  const int t = threadIdx.x;
  const int b = blockIdx.x;
  const int i = b * 256 + t;
  const int v = (i < N_NODES) ? count[i] : 0;
  s[t] = v;
  __syncthreads();
  for (int off = 1; off < 256; off <<= 1) {
    int u = (t >= off) ? s[t - off] : 0;
    __syncthreads();
    s[t] += u;
    __syncthreads();
  }
  if (t == 255)
    __hip_atomic_store(&status[b], (1ULL << 32) | (unsigned)s[255],
                       __ATOMIC_RELEASE, __HIP_MEMORY_SCOPE_AGENT);
  int contrib = 0;
  if (t < b) {  // b <= 156 < 255: one predecessor per thread
    unsigned long long sv;
    do {
      sv = __hip_atomic_load(&status[t], __ATOMIC_ACQUIRE,
                             __HIP_MEMORY_SCOPE_AGENT);
    } while (!(sv >> 32));
    contrib = (int)(unsigned)sv;
  }
  for (int o = 32; o > 0; o >>= 1) contrib += __shfl_down(contrib, o, 64);
  if ((t & 63) == 0) wsum[t >> 6] = contrib;
  __syncthreads();
  const int boffv = wsum[0] + wsum[1] + wsum[2] + wsum[3];
  if (i < N_NODES) cursor[i] = boffv + s[t] - v;
}

// ---------------------------------------------------------------------------
// K4: scatter -> packed u64: dst[51:36] | col[35:20] | e[19:0]
// ---------------------------------------------------------------------------
__global__ void scatter_kernel(const int* __restrict__ rowI,
                               const int* __restrict__ colI,
                               int* __restrict__ cursor,
                               unsigned long long* __restrict__ packed) {
  int e = blockIdx.x * 256 + threadIdx.x;
  if (e < N_EDGES) {
    const int r = rowI[e];
    const int c = colI[e];
    const int p = atomicAdd(&cursor[r], 1);
    packed[p] = ((unsigned long long)r << 36) | ((unsigned long long)c << 20) |
                (unsigned)e;
  }
}

// ---------------------------------------------------------------------------
// K5: fused filter + modulate + segmented reduce, sorted order.
// T14 prefetch with NAMED SCALAR registers (no arrays -> no scratch).
// ---------------------------------------------------------------------------
__global__ __launch_bounds__(256, 3) void edge_fused_kernel(
    const unsigned long long* __restrict__ packed, const float* __restrict__ rbf,
    const float* __restrict__ W1, const float* __restrict__ b1,
    const float* __restrict__ W2, const float* __restrict__ b2,
    const unsigned short* __restrict__ hbf, float* __restrict__ outp) {
  __shared__ __align__(16) char pool[IN_CH * W2_STR * 2];  // 34816 B

  unsigned short* sHv = (unsigned short*)pool;                            // 17408
  unsigned short* sT = (unsigned short*)pool;                             // overlap
  unsigned short* sRbf = (unsigned short*)(pool + TILE_M * HV_STR * 2);   // 9216
  int* sAux = (int*)(pool + TILE_M * HV_STR * 2 + TILE_M * RBF_STR * 2);  // 256

  const int t = threadIdx.x;
  const int lane = t & 63;
  const int l31 = lane & 31;
  const int lhalf = lane >> 5;
  const int wv = t >> 6;
  const int nbase = wv * 32 + l31;

  // ---- weight fragments (pool reused twice) ----
  {
    unsigned short* sW1T = (unsigned short*)pool;
    const int k = t >> 2;
    const int c0 = (t & 3) * 32;
#pragma unroll
    for (int i = 0; i < 8; ++i) {
      float4 v = *(const float4*)(W1 + k * OUT_CH + c0 + 4 * i);
      sW1T[(c0 + 4 * i + 0) * W1_STR + k] = f2bf(v.x);
      sW1T[(c0 + 4 * i + 1) * W1_STR + k] = f2bf(v.y);
      sW1T[(c0 + 4 * i + 2) * W1_STR + k] = f2bf(v.z);
      sW1T[(c0 + 4 * i + 3) * W1_STR + k] = f2bf(v.w);
    }
  }
  __syncthreads();
  bf16x8 B1[4];
  {
    const unsigned short* sW1T = (const unsigned short*)pool;
#pragma unroll
    for (int kk = 0; kk < 4; ++kk)
      B1[kk] = *(const bf16x8*)&sW1T[nbase * W1_STR + kk * 16 + lhalf * 8];
  }
  __syncthreads();
  {
    unsigned short* sW2T = (unsigned short*)pool;
    const int k2 = t >> 1;
    const int d0 = (t & 1) * 64;
#pragma unroll
    for (int i = 0; i < 16; ++i) {
      float4 v = *(const float4*)(W2 + k2 * OUT_CH + d0 + 4 * i);
      sW2T[(d0 + 4 * i + 0) * W2_STR + k2] = f2bf(v.x);
      sW2T[(d0 + 4 * i + 1) * W2_STR + k2] = f2bf(v.y);
      sW2T[(d0 + 4 * i + 2) * W2_STR + k2] = f2bf(v.z);
      sW2T[(d0 + 4 * i + 3) * W2_STR + k2] = f2bf(v.w);
    }
  }
  __syncthreads();
  bf16x8 B2[8];
  {
    const unsigned short* sW2T = (const unsigned short*)pool;
#pragma unroll
    for (int kk = 0; kk < 8; ++kk)
      B2[kk] = *(const bf16x8*)&sW2T[nbase * W2_STR + kk * 16 + lhalf * 8];
  }
  const float b1v = b1[nbase];
  const float b2v = b2[nbase];

  const int m4 = t >> 2;        // rbf row this thread stages
  const int kq = (t & 3) * 16;  // rbf col quarter
  const int rrow = t >> 4;      // hv chunk row base (0..15)
  const int c8 = (t & 15) * 8;  // hv ushort offset within row

  // prefetch registers: individual named scalars only (NO arrays)
  float4 rb0, rb1, rb2, rb3;
  uint4 hq0, hq1, hq2, hq3;
  int auxv = 0;

#define PREFETCH(EB)                                                          \
  do {                                                                        \
    const unsigned long long pkm = packed[(EB) + m4];                         \
    const float* psrc = rbf + (size_t)(pkm & 0xFFFFFu) * NUM_RBF + kq;        \
    rb0 = *(const float4*)(psrc + 0);                                         \
    rb1 = *(const float4*)(psrc + 4);                                         \
    rb2 = *(const float4*)(psrc + 8);                                         \
    rb3 = *(const float4*)(psrc + 12);                                        \
    hq0 = *(const uint4*)(hbf +                                               \
        (size_t)((packed[(EB) + 0 + rrow] >> 20) & 0xFFFFu) * OUT_CH + c8);   \
    hq1 = *(const uint4*)(hbf +                                               \
        (size_t)((packed[(EB) + 16 + rrow] >> 20) & 0xFFFFu) * OUT_CH + c8);  \
    hq2 = *(const uint4*)(hbf +                                               \
        (size_t)((packed[(EB) + 32 + rrow] >> 20) & 0xFFFFu) * OUT_CH + c8);  \
    hq3 = *(const uint4*)(hbf +                                               \
        (size_t)((packed[(EB) + 48 + rrow] >> 20) & 0xFFFFu) * OUT_CH + c8);  \
    if (t < TILE_M) auxv = (int)(packed[(EB) + t] >> 36);                     \
  } while (0)

  int tile = blockIdx.x;
  if (tile < NTILES) PREFETCH(tile * TILE_M);

  for (; tile < NTILES; tile += gridDim.x) {
    __syncthreads();  // (a) prev GEMM2's sT/sAux reads complete

    // ---- store staged regs -> LDS ----
    {
      ushort4 p;
      p.x = f2bf(rb0.x); p.y = f2bf(rb0.y); p.z = f2bf(rb0.z); p.w = f2bf(rb0.w);
      *(ushort4*)&sRbf[m4 * RBF_STR + kq + 0] = p;
      p.x = f2bf(rb1.x); p.y = f2bf(rb1.y); p.z = f2bf(rb1.z); p.w = f2bf(rb1.w);
      *(ushort4*)&sRbf[m4 * RBF_STR + kq + 4] = p;
      p.x = f2bf(rb2.x); p.y = f2bf(rb2.y); p.z = f2bf(rb2.z); p.w = f2bf(rb2.w);
      *(ushort4*)&sRbf[m4 * RBF_STR + kq + 8] = p;
      p.x = f2bf(rb3.x); p.y = f2bf(rb3.y); p.z = f2bf(rb3.z); p.w = f2bf(rb3.w);
      *(ushort4*)&sRbf[m4 * RBF_STR + kq + 12] = p;
    }
    *(uint4*)&sHv[(rrow + 0) * HV_STR + c8] = hq0;
    *(uint4*)&sHv[(rrow + 16) * HV_STR + c8] = hq1;
    *(uint4*)&sHv[(rrow + 32) * HV_STR + c8] = hq2;
    *(uint4*)&sHv[(rrow + 48) * HV_STR + c8] = hq3;
    if (t < TILE_M) sAux[t] = auxv;
    __syncthreads();  // (b)

    // ---- prefetch next tile (latency hides under GEMM1 + GEMM2) ----
    const int tn = tile + gridDim.x;
    if (tn < NTILES) PREFETCH(tn * TILE_M);

    // ---- h values from LDS (before sT overwrites sHv) ----
    float hv[2][16];
#pragma unroll
    for (int mt = 0; mt < 2; ++mt)
#pragma unroll
      for (int r = 0; r < 16; ++r) {
        const int rowm = mt * 32 + (r & 3) + 8 * (r >> 2) + 4 * lhalf;
        hv[mt][r] = bf2f(sHv[rowm * HV_STR + nbase]);
      }
    __syncthreads();  // (b2) sHv dead; sT may overwrite

    // ---- GEMM1: sT = bf16(relu(rbf @ W1 + b1)) ----
#pragma unroll
    for (int mt = 0; mt < 2; ++mt) {
      f32x16 acc = {0.f, 0.f, 0.f, 0.f, 0.f, 0.f, 0.f, 0.f,
                    0.f, 0.f, 0.f, 0.f, 0.f, 0.f, 0.f, 0.f};
#pragma unroll
      for (int kk = 0; kk < 4; ++kk) {
        bf16x8 A = *(const bf16x8*)&sRbf[(mt * 32 + l31) * RBF_STR + kk * 16 + lhalf * 8];
        acc = __builtin_amdgcn_mfma_f32_32x32x16_bf16(A, B1[kk], acc, 0, 0, 0);
      }
#pragma unroll
      for (int r = 0; r < 16; ++r) {
        const int rowm = (r & 3) + 8 * (r >> 2) + 4 * lhalf;
        float v = acc[r] + b1v;
        v = v > 0.f ? v : 0.f;
        sT[(mt * 32 + rowm) * T_STR + nbase] = f2bf(v);
      }
    }
    __syncthreads();  // (c)

    // ---- GEMM2 + modulate + in-register segmented reduce ----
    float sum = 0.f;
    int curd = -1;
#pragma unroll
    for (int mt = 0; mt < 2; ++mt) {
      f32x16 acc = {0.f, 0.f, 0.f, 0.f, 0.f, 0.f, 0.f, 0.f,
                    0.f, 0.f, 0.f, 0.f, 0.f, 0.f, 0.f, 0.f};
#pragma unroll
      for (int kk = 0; kk < 8; ++kk) {
        bf16x8 A = *(const bf16x8*)&sT[(mt * 32 + l31) * T_STR + kk * 16 + lhalf * 8];
        acc = __builtin_amdgcn_mfma_f32_32x32x16_bf16(A, B2[kk], acc, 0, 0, 0);
      }
#pragma unroll
      for (int r = 0; r < 16; ++r) {
        const int rowm = mt * 32 + (r & 3) + 8 * (r >> 2) + 4 * lhalf;
        const float m = hv[mt][r] * (acc[r] + b2v);
        const int d = sAux[rowm];
        if (d != curd) {
          if (curd >= 0) atomicAdd(&outp[(size_t)curd * OUT_CH + nbase], sum);
          curd = d;
          sum = m;
        } else {
          sum += m;
        }
      }
    }
    atomicAdd(&outp[(size_t)curd * OUT_CH + nbase], sum);
  }
#undef PREFETCH
}

// ---------------------------------------------------------------------------
// Fallback: natural-order edge kernel (ws too small)
// ---------------------------------------------------------------------------
__global__ __launch_bounds__(256, 3) void edge_atomic_kernel(
    const int* __restrict__ eidx, const float* __restrict__ rbf,
    const float* __restrict__ W1, const float* __restrict__ b1,
    const float* __restrict__ W2, const float* __restrict__ b2,
    const unsigned short* __restrict__ hbf, float* __restrict__ outp) {
  __shared__ __align__(16) char pool[IN_CH * W2_STR * 2];

  unsigned short* sHv = (unsigned short*)pool;
  unsigned short* sT = (unsigned short*)pool;
  unsigned short* sRbf = (unsigned short*)(pool + TILE_M * HV_STR * 2);
  int* sAux = (int*)(pool + TILE_M * HV_STR * 2 + TILE_M * RBF_STR * 2);

  const int t = threadIdx.x;
  const int lane = t & 63;
  const int l31 = lane & 31;
  const int lhalf = lane >> 5;
  const int wv = t >> 6;
  const int nbase = wv * 32 + l31;

  {
    unsigned short* sW1T = (unsigned short*)pool;
    const int k = t >> 2;
    const int c0 = (t & 3) * 32;
#pragma unroll
    for (int i = 0; i < 8; ++i) {
      float4 v = *(const float4*)(W1 + k * OUT_CH + c0 + 4 * i);
      sW1T[(c0 + 4 * i + 0) * W1_STR + k] = f2bf(v.x);
      sW1T[(c0 + 4 * i + 1) * W1_STR + k] = f2bf(v.y);
      sW1T[(c0 + 4 * i + 2) * W1_STR + k] = f2bf(v.z);
      sW1T[(c0 + 4 * i + 3) * W1_STR + k] = f2bf(v.w);
    }
  }
  __syncthreads();
  bf16x8 B1[4];
  {
    const unsigned short* sW1T = (const unsigned short*)pool;
#pragma unroll
    for (int kk = 0; kk < 4; ++kk)
      B1[kk] = *(const bf16x8*)&sW1T[nbase * W1_STR + kk * 16 + lhalf * 8];
  }
  __syncthreads();
  {
    unsigned short* sW2T = (unsigned short*)pool;
    const int k2 = t >> 1;
    const int d0 = (t & 1) * 64;
#pragma unroll
    for (int i = 0; i < 16; ++i) {
      float4 v = *(const float4*)(W2 + k2 * OUT_CH + d0 + 4 * i);
      sW2T[(d0 + 4 * i + 0) * W2_STR + k2] = f2bf(v.x);
      sW2T[(d0 + 4 * i + 1) * W2_STR + k2] = f2bf(v.y);
      sW2T[(d0 + 4 * i + 2) * W2_STR + k2] = f2bf(v.z);
      sW2T[(d0 + 4 * i + 3) * W2_STR + k2] = f2bf(v.w);
    }
  }
  __syncthreads();
  bf16x8 B2[8];
  {
    const unsigned short* sW2T = (const unsigned short*)pool;
#pragma unroll
    for (int kk = 0; kk < 8; ++kk)
      B2[kk] = *(const bf16x8*)&sW2T[nbase * W2_STR + kk * 16 + lhalf * 8];
  }
  const float b1v = b1[nbase];
  const float b2v = b2[nbase];

  const int* rowI = eidx;
  const int* colI = eidx + N_EDGES;

  for (int tile = blockIdx.x; tile < NTILES; tile += gridDim.x) {
    const int ebase = tile * TILE_M;
    __syncthreads();
    {
      const int m = t >> 2;
      const int kq = (t & 3) * 16;
      const float* src = rbf + (size_t)(ebase + m) * NUM_RBF + kq;
#pragma unroll
      for (int i = 0; i < 4; ++i) {
        float4 v = *(const float4*)(src + 4 * i);
        ushort4 p;
        p.x = f2bf(v.x); p.y = f2bf(v.y); p.z = f2bf(v.z); p.w = f2bf(v.w);
        *(ushort4*)&sRbf[m * RBF_STR + kq + 4 * i] = p;
      }
#pragma unroll
      for (int i = 0; i < 4; ++i) {
        const int chunk = t + 256 * i;
        const int row = chunk >> 4;
        const int c8 = (chunk & 15) * 8;
        const int col = colI[ebase + row];
        *(uint4*)&sHv[row * HV_STR + c8] =
            *(const uint4*)(hbf + (size_t)col * OUT_CH + c8);
      }
      if (t < TILE_M) sAux[t] = rowI[ebase + t];
    }
    __syncthreads();

    float hv[2][16];
#pragma unroll
    for (int mt = 0; mt < 2; ++mt)
#pragma unroll
      for (int r = 0; r < 16; ++r) {
        const int rowm = mt * 32 + (r & 3) + 8 * (r >> 2) + 4 * lhalf;
        hv[mt][r] = bf2f(sHv[rowm * HV_STR + nbase]);
      }
    __syncthreads();

#pragma unroll
    for (int mt = 0; mt < 2; ++mt) {
      f32x16 acc = {0.f, 0.f, 0.f, 0.f, 0.f, 0.f, 0.f, 0.f,
                    0.f, 0.f, 0.f, 0.f, 0.f, 0.f, 0.f, 0.f};
#pragma unroll
      for (int kk = 0; kk < 4; ++kk) {
        bf16x8 A = *(const bf16x8*)&sRbf[(mt * 32 + l31) * RBF_STR + kk * 16 + lhalf * 8];
        acc = __builtin_amdgcn_mfma_f32_32x32x16_bf16(A, B1[kk], acc, 0, 0, 0);
      }
#pragma unroll
      for (int r = 0; r < 16; ++r) {
        const int rowm = (r & 3) + 8 * (r >> 2) + 4 * lhalf;
        float v = acc[r] + b1v;
        v = v > 0.f ? v : 0.f;
        sT[(mt * 32 + rowm) * T_STR + nbase] = f2bf(v);
      }
    }
    __syncthreads();

    float sum = 0.f;
    int curd = -1;
#pragma unroll
    for (int mt = 0; mt < 2; ++mt) {
      f32x16 acc = {0.f, 0.f, 0.f, 0.f, 0.f, 0.f, 0.f, 0.f,
                    0.f, 0.f, 0.f, 0.f, 0.f, 0.f, 0.f, 0.f};
#pragma unroll
      for (int kk = 0; kk < 8; ++kk) {
        bf16x8 A = *(const bf16x8*)&sT[(mt * 32 + l31) * T_STR + kk * 16 + lhalf * 8];
        acc = __builtin_amdgcn_mfma_f32_32x32x16_bf16(A, B2[kk], acc, 0, 0, 0);
      }
#pragma unroll
      for (int r = 0; r < 16; ++r) {
        const int rowm = mt * 32 + (r & 3) + 8 * (r >> 2) + 4 * lhalf;
        const float m = hv[mt][r] * (acc[r] + b2v);
        const int d = sAux[rowm];
        if (d != curd) {
          if (curd >= 0) atomicAdd(&outp[(size_t)curd * OUT_CH + nbase], sum);
          curd = d;
          sum = m;
        } else {
          sum += m;
        }
      }
    }
    atomicAdd(&outp[(size_t)curd * OUT_CH + nbase], sum);
  }
}

// ---------------------------------------------------------------------------
extern "C" void kernel_launch(void* const* d_in, const int* in_sizes, int n_in,
                              void* d_out, int out_size, void* d_ws, size_t ws_size,
                              hipStream_t stream) {
  const float* x    = (const float*)d_in[0];
  const int*   eidx = (const int*)d_in[1];
  const float* rbf  = (const float*)d_in[2];
  const float* W1   = (const float*)d_in[3];
  const float* b1   = (const float*)d_in[4];
  const float* W2   = (const float*)d_in[5];
  const float* b2   = (const float*)d_in[6];
  const float* Wl   = (const float*)d_in[7];
  const float* bl   = (const float*)d_in[8];
  float* out = (float*)d_out;

  char* ws = (char*)d_ws;
  const size_t HBF_B = (size_t)N_NODES * OUT_CH * 2;   // 10,240,000
  const size_t PK_B = (size_t)N_EDGES * 8;             //  5,120,000
  const size_t CNT_B = (size_t)N_NODES * 4;            //    160,000 (x2)
  const size_t ST_B = 1280;
  const size_t need = HBF_B + PK_B + 2 * CNT_B + ST_B + 64;

  size_t off = 0;
  unsigned short* hbf = (unsigned short*)(ws + off); off += HBF_B;
  unsigned long long* packed = (unsigned long long*)(ws + off); off += PK_B;
  int* count  = (int*)(ws + off); off += CNT_B;
  int* cursor = (int*)(ws + off); off += CNT_B;
  unsigned long long* status = (unsigned long long*)(ws + off); off += ST_B;

  const int* rowI = eidx;
  const int* colI = eidx + N_EDGES;

  if (ws_size >= need) {
    k1_kernel<<<K1_GRID, 256, 0, stream>>>(x, Wl, bl, hbf, count, out);
    hist_kernel<<<(N_EDGES + 255) / 256, 256, 0, stream>>>(rowI, count, status);
    scan_kernel<<<NSCB, 256, 0, stream>>>(count, status, cursor);
    scatter_kernel<<<(N_EDGES + 255) / 256, 256, 0, stream>>>(
        rowI, colI, cursor, packed);
    edge_fused_kernel<<<EDGE_GRID, 256, 0, stream>>>(
        packed, rbf, W1, b1, W2, b2, hbf, out);
  } else {
    hipMemsetAsync(out, 0, (size_t)N_NODES * OUT_CH * sizeof(float), stream);
    k1_kernel<<<NB_NODE, 256, 0, stream>>>(x, Wl, bl, hbf, nullptr, nullptr);
    edge_atomic_kernel<<<EDGE_GRID, 256, 0, stream>>>(
        eidx, rbf, W1, b1, W2, b2, hbf, out);
  }
}